// Round 7
// baseline (98.089 us; speedup 1.0000x reference)
//
#include <hip/hip_runtime.h>
#include <hip/hip_bf16.h>

#define NHEADS 6
#define HD 32
#define CDIM 192
#define NTOK 64
#define NREL 225
#define PDIM 12
#define IMG 256
#define NWW 32
#define NWIN 2048
#define SCALE 0.17677669529663687f
#define INV_SCALE 5.656854249492381f

typedef __attribute__((ext_vector_type(8))) short v8s;
typedef __attribute__((ext_vector_type(4))) float v4f;

#define QKS 40   // ks row stride (ushort) = 80B
#define VTS 72   // vt row stride = 144B (rows indexed by d, cols by k')
#define PTS 72   // pt row stride = 144B (cols by k')

__device__ __forceinline__ unsigned pkbf(float x, float y) {
    __hip_bfloat162 h = __float22bfloat162_rn(make_float2(x, y));
    union { __hip_bfloat162 h; unsigned u; } c; c.h = h;
    return c.u;
}

__device__ __forceinline__ void ln_relu12(const float* x, const float* g,
                                          const float* be, float* y) {
    float m = 0.f;
#pragma unroll
    for (int i = 0; i < PDIM; ++i) m += x[i];
    m *= (1.f / PDIM);
    float v = 0.f;
#pragma unroll
    for (int i = 0; i < PDIM; ++i) { float d = x[i] - m; v += d * d; }
    v *= (1.f / PDIM);
    float inv = rsqrtf(v + 1e-5f);
#pragma unroll
    for (int i = 0; i < PDIM; ++i) {
        float t = (x[i] - m) * inv * g[i] + be[i];
        y[i] = t > 0.f ? t : 0.f;
    }
}

// 1 block: compact 225x6 table, pre-multiplied by 1/SCALE, head-major
__global__ __launch_bounds__(256) void posbias_kernel(
    const float* __restrict__ wp, const float* __restrict__ bp,
    const float* __restrict__ g1, const float* __restrict__ be1,
    const float* __restrict__ w1, const float* __restrict__ b1,
    const float* __restrict__ g2, const float* __restrict__ be2,
    const float* __restrict__ w2, const float* __restrict__ b2,
    const float* __restrict__ g3, const float* __restrict__ be3,
    const float* __restrict__ w3, const float* __restrict__ b3,
    float* __restrict__ p_t)
{
    int r = threadIdx.x;
    if (r >= NREL) return;
    float x0 = (float)(r / 15 - 7);
    float x1 = (float)(r % 15 - 7);
    float h[PDIM], y[PDIM];
#pragma unroll
    for (int o = 0; o < PDIM; ++o)
        h[o] = x0 * wp[o] + x1 * wp[PDIM + o] + bp[o];
    ln_relu12(h, g1, be1, y);
#pragma unroll
    for (int o = 0; o < PDIM; ++o) {
        float a = b1[o];
#pragma unroll
        for (int i = 0; i < PDIM; ++i) a += y[i] * w1[i * PDIM + o];
        h[o] = a;
    }
    ln_relu12(h, g2, be2, y);
#pragma unroll
    for (int o = 0; o < PDIM; ++o) {
        float a = b2[o];
#pragma unroll
        for (int i = 0; i < PDIM; ++i) a += y[i] * w2[i * PDIM + o];
        h[o] = a;
    }
    ln_relu12(h, g3, be3, y);
#pragma unroll
    for (int o = 0; o < NHEADS; ++o) {
        float a = b3[o];
#pragma unroll
        for (int i = 0; i < PDIM; ++i) a += y[i] * w3[i * NHEADS + o];
        p_t[o * NREL + r] = a * INV_SCALE;
    }
}

__global__ __launch_bounds__(256) void win_attn_mfma(
    const float* __restrict__ qkv, const float* __restrict__ p_t,
    float* __restrict__ out)
{
    __shared__ __align__(16) unsigned short ks[NTOK * QKS]; // K row-major bf16
    __shared__ __align__(16) unsigned short vt[HD * VTS];   // V^T bf16, cols = k'
    __shared__ __align__(16) unsigned short pt[NTOK * PTS]; // P bf16, cols = k'
    __shared__ float psh[NREL];

    const int t = threadIdx.x;
    const int head = blockIdx.x >> 11;
    const int win  = blockIdx.x & (NWIN - 1);
    const int b    = win >> 10;
    const int bh   = (win >> 5) & 31;
    const int bw   = win & 31;

    const int lane = t & 63;
    const int wave = t >> 6;
    const int lw = lane & 15;
    const int lg = lane >> 4;
    const int rowbase = wave * 16;

    const size_t SST = (size_t)2 * IMG * IMG * CDIM;
    const float* basep = qkv + (size_t)b * IMG * IMG * CDIM + head * HD;

    auto toff = [&](int tok) -> size_t {
        return ((size_t)(bh * 8 + (tok >> 3)) * IMG + (bw * 8 + (tok & 7))) * CDIM;
    };

    // ---------- issue ALL global loads first (max MLP) ----------
    float pshv = 0.f;
    if (t < NREL) pshv = p_t[head * NREL + t];

    // K: 2 passes, thread covers (tok, tok+32) at d-slot (t&7)*4
    const int tokK = t >> 3;
    const int dK   = (t & 7) * 4;
    float4 k40 = *(const float4*)(basep + SST + toff(tokK) + dK);
    float4 k41 = *(const float4*)(basep + SST + toff(tokK + 32) + dK);

    // V: thread covers token pair (ta, ta+16) at 4 d-values
    const int u  = t & 31;
    const int dg = t >> 5;
    const int ta = (u & 15) + (u >> 4) * 32;   // paired with ta+16 (k' adjacent)
    const int db = dg * 4;
    float4 va  = *(const float4*)(basep + 2 * SST + toff(ta) + db);
    float4 vb4 = *(const float4*)(basep + 2 * SST + toff(ta + 16) + db);

    // Q A-fragment direct
    const float* qp = basep + toff(rowbase + lw) + lg * 8;
    float4 q0 = *(const float4*)qp;
    float4 q1 = *(const float4*)(qp + 4);

    // ---------- convert + conflict-free packed LDS writes ----------
    if (t < NREL) psh[t] = pshv;

    uint2 kk0; kk0.x = pkbf(k40.x, k40.y); kk0.y = pkbf(k40.z, k40.w);
    uint2 kk1; kk1.x = pkbf(k41.x, k41.y); kk1.y = pkbf(k41.z, k41.w);
    *(uint2*)&ks[tokK * QKS + dK] = kk0;
    *(uint2*)&ks[(tokK + 32) * QKS + dK] = kk1;

    // k'(tok) = (tok&15)*4 + (tok>>4); k'(ta+16) = k'(ta)+1
    const int kpa = (u & 15) * 4 + (u >> 4) * 2;
    *(unsigned*)&vt[(db + 0) * VTS + kpa] = pkbf(va.x, vb4.x);
    *(unsigned*)&vt[(db + 1) * VTS + kpa] = pkbf(va.y, vb4.y);
    *(unsigned*)&vt[(db + 2) * VTS + kpa] = pkbf(va.z, vb4.z);
    *(unsigned*)&vt[(db + 3) * VTS + kpa] = pkbf(va.w, vb4.w);

    v8s a;
    {
        union { v8s v; unsigned x[4]; } au;
        au.x[0] = pkbf(q0.x, q0.y);
        au.x[1] = pkbf(q0.z, q0.w);
        au.x[2] = pkbf(q1.x, q1.y);
        au.x[3] = pkbf(q1.z, q1.w);
        a = au.v;
    }
    __syncthreads();   // ks, vt, psh visible

    // ---------- S' = Q K^T (C = 0) ----------
    v4f acc[4];
#pragma unroll
    for (int ct = 0; ct < 4; ++ct) {
        v4f z = {0.f, 0.f, 0.f, 0.f};
        v8s bfr = *(const v8s*)&ks[(ct * 16 + lw) * QKS + lg * 8];
        acc[ct] = __builtin_amdgcn_mfma_f32_16x16x32_bf16(a, bfr, z, 0, 0, 0);
    }

    // ---------- bias + exp (no max-sub; normalization deferred) ----------
    v4f rinv;
    {
        int base_r[4];
#pragma unroll
        for (int r = 0; r < 4; ++r) {
            int n = rowbase + lg * 4 + r;
            base_r[r] = ((n >> 3) - (lw >> 3) + 7) * 15 + (n & 7) - (lw & 7) + 7;
        }
        v4f s4 = {0.f, 0.f, 0.f, 0.f};
#pragma unroll
        for (int ct = 0; ct < 4; ++ct)
#pragma unroll
            for (int r = 0; r < 4; ++r) {
                float e = __expf((acc[ct][r] + psh[base_r[r] - ct * 30]) * SCALE);
                acc[ct][r] = e;
                s4[r] += e;
            }
#pragma unroll
        for (int off = 1; off < 16; off <<= 1)
#pragma unroll
            for (int r = 0; r < 4; ++r)
                s4[r] += __shfl_xor(s4[r], off);
#pragma unroll
        for (int r = 0; r < 4; ++r) rinv[r] = __builtin_amdgcn_rcpf(s4[r]);
        // P store: lane's 4 ct-values are contiguous in k' -> one b64 per row
#pragma unroll
        for (int r = 0; r < 4; ++r) {
            uint2 w;
            w.x = pkbf(acc[0][r], acc[1][r]);
            w.y = pkbf(acc[2][r], acc[3][r]);
            *(uint2*)&pt[(rowbase + lg * 4 + r) * PTS + lw * 4] = w;
        }
    }

    // ---------- O = (P V) * rinv   (both operands in k' order) ----------
    {
        v8s pa[2];
#pragma unroll
        for (int kt = 0; kt < 2; ++kt)
            pa[kt] = *(const v8s*)&pt[(rowbase + lw) * PTS + kt * 32 + lg * 8];
        v4f acc2[2] = {};
#pragma unroll
        for (int dt = 0; dt < 2; ++dt)
#pragma unroll
            for (int kt = 0; kt < 2; ++kt) {
                v8s vb = *(const v8s*)&vt[(dt * 16 + lw) * VTS + kt * 32 + lg * 8];
                acc2[dt] = __builtin_amdgcn_mfma_f32_16x16x32_bf16(pa[kt], vb, acc2[dt], 0, 0, 0);
            }
#pragma unroll
        for (int dt = 0; dt < 2; ++dt)
#pragma unroll
            for (int r = 0; r < 4; ++r) {
                int n = rowbase + lg * 4 + r;
                size_t off = (((size_t)b * IMG + bh * 8 + (n >> 3)) * IMG
                              + (bw * 8 + (n & 7))) * CDIM + head * HD + dt * 16 + lw;
                out[off] = acc2[dt][r] * rinv[r];
            }
    }
}

extern "C" void kernel_launch(void* const* d_in, const int* in_sizes, int n_in,
                              void* d_out, int out_size, void* d_ws, size_t ws_size,
                              hipStream_t stream) {
    const float* qkv = (const float*)d_in[0];
    const float* wp  = (const float*)d_in[1];
    const float* bp  = (const float*)d_in[2];
    const float* g1  = (const float*)d_in[3];
    const float* be1 = (const float*)d_in[4];
    const float* w1  = (const float*)d_in[5];
    const float* b1  = (const float*)d_in[6];
    const float* g2  = (const float*)d_in[7];
    const float* be2 = (const float*)d_in[8];
    const float* w2  = (const float*)d_in[9];
    const float* b2  = (const float*)d_in[10];
    const float* g3  = (const float*)d_in[11];
    const float* be3 = (const float*)d_in[12];
    const float* w3  = (const float*)d_in[13];
    const float* b3  = (const float*)d_in[14];

    float* p_t = (float*)d_ws;  // 6*225 floats (head-major, pre-scaled)
    posbias_kernel<<<1, 256, 0, stream>>>(wp, bp, g1, be1, w1, b1,
                                          g2, be2, w2, b2, g3, be3, w3, b3, p_t);
    win_attn_mfma<<<NWIN * NHEADS, 256, 0, stream>>>(qkv, p_t, (float*)d_out);
}

// Round 8
// 92.447 us; speedup vs baseline: 1.0610x; 1.0610x over previous
//
#include <hip/hip_runtime.h>
#include <hip/hip_bf16.h>

#define NHEADS 6
#define HD 32
#define CDIM 192
#define NTOK 64
#define NREL 225
#define PDIM 12
#define IMG 256
#define NWIN 2048
#define SCALE 0.17677669529663687f
#define INV_SCALE 5.656854249492381f

typedef __attribute__((ext_vector_type(8))) short v8s;
typedef __attribute__((ext_vector_type(4))) float v4f;

#define KS2 200  // ks row stride (ushort): 400B, 16B-mult, 2-way max on reads
#define VTS 72   // vt row stride: 144B
#define PTS 72   // pt row stride: 144B

__device__ __forceinline__ unsigned pkbf(float x, float y) {
    __hip_bfloat162 h = __float22bfloat162_rn(make_float2(x, y));
    union { __hip_bfloat162 h; unsigned u; } c; c.h = h;
    return c.u;
}

__device__ __forceinline__ void ln_relu12(const float* x, const float* g,
                                          const float* be, float* y) {
    float m = 0.f;
#pragma unroll
    for (int i = 0; i < PDIM; ++i) m += x[i];
    m *= (1.f / PDIM);
    float v = 0.f;
#pragma unroll
    for (int i = 0; i < PDIM; ++i) { float d = x[i] - m; v += d * d; }
    v *= (1.f / PDIM);
    float inv = rsqrtf(v + 1e-5f);
#pragma unroll
    for (int i = 0; i < PDIM; ++i) {
        float t = (x[i] - m) * inv * g[i] + be[i];
        y[i] = t > 0.f ? t : 0.f;
    }
}

__global__ __launch_bounds__(256) void win_attn_fused(
    const float* __restrict__ qkv,
    const float* __restrict__ wp, const float* __restrict__ bp,
    const float* __restrict__ g1, const float* __restrict__ be1,
    const float* __restrict__ w1, const float* __restrict__ b1,
    const float* __restrict__ g2, const float* __restrict__ be2,
    const float* __restrict__ w2, const float* __restrict__ b2,
    const float* __restrict__ g3, const float* __restrict__ be3,
    const float* __restrict__ w3, const float* __restrict__ b3,
    float* __restrict__ out)
{
    __shared__ __align__(16) unsigned short ks[NTOK * KS2];  // K, all heads
    __shared__ __align__(16) unsigned short vt[CDIM * VTS];  // V^T, rows h*32+d
    __shared__ __align__(16) unsigned short pt[NTOK * PTS];  // P (wave-private)
    __shared__ float psh[NHEADS * NREL];

    const int t = threadIdx.x;
    const int win = blockIdx.x;                // window-major
    const int b  = win >> 10;
    const int bh = (win >> 5) & 31;
    const int bw = win & 31;

    const int lane = t & 63;
    const int wave = t >> 6;
    const int lw = lane & 15;
    const int lg = lane >> 4;
    const int rowbase = wave * 16;

    const size_t PL = (size_t)2 * IMG * IMG * CDIM;
    const float* qplane = qkv + (size_t)b * IMG * IMG * CDIM;
    const float* kplane = qplane + PL;
    const float* vplane = kplane + PL;

    auto pixoff = [&](int tok) -> size_t {
        return ((size_t)(bh * 8 + (tok >> 3)) * IMG + (bw * 8 + (tok & 7))) * CDIM;
    };

    // ---------- K: fully contiguous streaming (12 x 1KB per wave) ----------
#pragma unroll
    for (int pass = 0; pass < 12; ++pass) {
        int fidx = t + pass * 256;            // float4 index, 0..3071
        int s   = fidx / 384;                 // image-row strip in window
        int rem = fidx - s * 384;
        int j1  = rem / 48;                   // pixel within strip
        int f   = rem - j1 * 48;              // float4 within 192-float row
        float4 k4 = *(const float4*)(kplane
                     + ((size_t)(bh * 8 + s) * IMG + (bw * 8 + j1)) * CDIM + f * 4);
        uint2 kk; kk.x = pkbf(k4.x, k4.y); kk.y = pkbf(k4.z, k4.w);
        *(uint2*)&ks[(s * 8 + j1) * KS2 + f * 4] = kk;
    }

    // ---------- V: per-head k'-paired transpose (conflict-free b32) ----------
    {
        const int u  = t & 31;
        const int dg = t >> 5;                // 0..7
        const int ta = (u & 15) + (u >> 4) * 32;
        const int db = dg * 4;
        const int kpa = (u & 15) * 4 + (u >> 4) * 2;
        const size_t offa = pixoff(ta), offb = pixoff(ta + 16);
#pragma unroll
        for (int h = 0; h < NHEADS; ++h) {
            float4 va = *(const float4*)(vplane + offa + h * HD + db);
            float4 vb = *(const float4*)(vplane + offb + h * HD + db);
            int row = h * HD + db;
            *(unsigned*)&vt[(row + 0) * VTS + kpa] = pkbf(va.x, vb.x);
            *(unsigned*)&vt[(row + 1) * VTS + kpa] = pkbf(va.y, vb.y);
            *(unsigned*)&vt[(row + 2) * VTS + kpa] = pkbf(va.z, vb.z);
            *(unsigned*)&vt[(row + 3) * VTS + kpa] = pkbf(va.w, vb.w);
        }
    }

    // ---------- Q: preload all 6 heads' A-fragments ----------
    v8s aq[NHEADS];
    {
        const size_t qoff = pixoff(rowbase + lw);
#pragma unroll
        for (int h = 0; h < NHEADS; ++h) {
            const float* qp = qplane + qoff + h * HD + lg * 8;
            float4 q0 = *(const float4*)qp;
            float4 q1 = *(const float4*)(qp + 4);
            union { v8s v; unsigned x[4]; } au;
            au.x[0] = pkbf(q0.x, q0.y);
            au.x[1] = pkbf(q0.z, q0.w);
            au.x[2] = pkbf(q1.x, q1.y);
            au.x[3] = pkbf(q1.z, q1.w);
            aq[h] = au.v;
        }
    }

    // ---------- fused DynamicPosBias MLP (threads 0..224) ----------
    if (t < NREL) {
        float x0 = (float)(t / 15 - 7);
        float x1 = (float)(t % 15 - 7);
        float h[PDIM], y[PDIM];
#pragma unroll
        for (int o = 0; o < PDIM; ++o)
            h[o] = x0 * wp[o] + x1 * wp[PDIM + o] + bp[o];
        ln_relu12(h, g1, be1, y);
#pragma unroll
        for (int o = 0; o < PDIM; ++o) {
            float a = b1[o];
#pragma unroll
            for (int i = 0; i < PDIM; ++i) a += y[i] * w1[i * PDIM + o];
            h[o] = a;
        }
        ln_relu12(h, g2, be2, y);
#pragma unroll
        for (int o = 0; o < PDIM; ++o) {
            float a = b2[o];
#pragma unroll
            for (int i = 0; i < PDIM; ++i) a += y[i] * w2[i * PDIM + o];
            h[o] = a;
        }
        ln_relu12(h, g3, be3, y);
#pragma unroll
        for (int o = 0; o < NHEADS; ++o) {
            float a = b3[o];
#pragma unroll
            for (int i = 0; i < PDIM; ++i) a += y[i] * w3[i * NHEADS + o];
            psh[o * NREL + t] = a * INV_SCALE;
        }
    }
    __syncthreads();   // ks, vt, psh visible to all waves; last barrier

    // ---------- per-row constants ----------
    int base_r[4];
    size_t ooff[4];
#pragma unroll
    for (int r = 0; r < 4; ++r) {
        int n = rowbase + lg * 4 + r;
        base_r[r] = ((n >> 3) - (lw >> 3) + 7) * 15 + (n & 7) - (lw & 7) + 7;
        ooff[r] = ((size_t)(b * IMG + bh * 8 + (n >> 3)) * IMG
                   + (bw * 8 + (n & 7))) * CDIM;
    }

    // ---------- 6 independent head iterations per wave ----------
#pragma unroll
    for (int h = 0; h < NHEADS; ++h) {
        // S' = Q K^T
        v4f acc[4];
#pragma unroll
        for (int ct = 0; ct < 4; ++ct) {
            v4f z = {0.f, 0.f, 0.f, 0.f};
            v8s bfr = *(const v8s*)&ks[(ct * 16 + lw) * KS2 + h * HD + lg * 8];
            acc[ct] = __builtin_amdgcn_mfma_f32_16x16x32_bf16(aq[h], bfr, z, 0, 0, 0);
        }
        // bias + exp (no max-sub), sum, deferred normalization
        const float* ph = &psh[h * NREL];
        v4f s4 = {0.f, 0.f, 0.f, 0.f};
#pragma unroll
        for (int ct = 0; ct < 4; ++ct)
#pragma unroll
            for (int r = 0; r < 4; ++r) {
                float e = __expf((acc[ct][r] + ph[base_r[r] - ct * 30]) * SCALE);
                acc[ct][r] = e;
                s4[r] += e;
            }
#pragma unroll
        for (int off = 1; off < 16; off <<= 1)
#pragma unroll
            for (int r = 0; r < 4; ++r)
                s4[r] += __shfl_xor(s4[r], off);
        v4f rinv;
#pragma unroll
        for (int r = 0; r < 4; ++r) rinv[r] = __builtin_amdgcn_rcpf(s4[r]);
        // P store (k'-packed, conflict-free b64; wave-private rows)
#pragma unroll
        for (int r = 0; r < 4; ++r) {
            uint2 w;
            w.x = pkbf(acc[0][r], acc[1][r]);
            w.y = pkbf(acc[2][r], acc[3][r]);
            *(uint2*)&pt[(rowbase + lg * 4 + r) * PTS + lw * 4] = w;
        }
        // O = (P V) * rinv
        v8s pa[2];
#pragma unroll
        for (int kt = 0; kt < 2; ++kt)
            pa[kt] = *(const v8s*)&pt[(rowbase + lw) * PTS + kt * 32 + lg * 8];
        v4f acc2[2] = {};
#pragma unroll
        for (int dt = 0; dt < 2; ++dt)
#pragma unroll
            for (int kt = 0; kt < 2; ++kt) {
                v8s vb = *(const v8s*)&vt[(h * HD + dt * 16 + lw) * VTS
                                          + kt * 32 + lg * 8];
                acc2[dt] = __builtin_amdgcn_mfma_f32_16x16x32_bf16(pa[kt], vb, acc2[dt], 0, 0, 0);
            }
#pragma unroll
        for (int dt = 0; dt < 2; ++dt)
#pragma unroll
            for (int r = 0; r < 4; ++r)
                out[ooff[r] + h * HD + dt * 16 + lw] = acc2[dt][r] * rinv[r];
    }
}

extern "C" void kernel_launch(void* const* d_in, const int* in_sizes, int n_in,
                              void* d_out, int out_size, void* d_ws, size_t ws_size,
                              hipStream_t stream) {
    const float* qkv = (const float*)d_in[0];
    win_attn_fused<<<NWIN, 256, 0, stream>>>(
        qkv,
        (const float*)d_in[1], (const float*)d_in[2],
        (const float*)d_in[3], (const float*)d_in[4],
        (const float*)d_in[5], (const float*)d_in[6],
        (const float*)d_in[7], (const float*)d_in[8],
        (const float*)d_in[9], (const float*)d_in[10],
        (const float*)d_in[11], (const float*)d_in[12],
        (const float*)d_in[13], (const float*)d_in[14],
        (float*)d_out);
}

// Round 9
// 88.257 us; speedup vs baseline: 1.1114x; 1.0475x over previous
//
#include <hip/hip_runtime.h>
#include <hip/hip_bf16.h>

#define NHEADS 6
#define HD 32
#define CDIM 192
#define NTOK 64
#define NREL 225
#define PDIM 12
#define IMG 256
#define NWIN 2048
#define SCALE 0.17677669529663687f
#define INV_SCALE 5.656854249492381f

typedef __attribute__((ext_vector_type(8))) short v8s;
typedef __attribute__((ext_vector_type(4))) float v4f;

#define KS2 200  // ks row stride (ushort): 400B (16B-mult, 4-bank row rotation)
#define VTS 72   // vt row stride: 144B
#define PTS 72   // pt row stride: 144B

__device__ __forceinline__ unsigned pkbf(float x, float y) {
    __hip_bfloat162 h = __float22bfloat162_rn(make_float2(x, y));
    union { __hip_bfloat162 h; unsigned u; } c; c.h = h;
    return c.u;
}

__device__ __forceinline__ void ln_relu12(const float* x, const float* g,
                                          const float* be, float* y) {
    float m = 0.f;
#pragma unroll
    for (int i = 0; i < PDIM; ++i) m += x[i];
    m *= (1.f / PDIM);
    float v = 0.f;
#pragma unroll
    for (int i = 0; i < PDIM; ++i) { float d = x[i] - m; v += d * d; }
    v *= (1.f / PDIM);
    float inv = rsqrtf(v + 1e-5f);
#pragma unroll
    for (int i = 0; i < PDIM; ++i) {
        float t = (x[i] - m) * inv * g[i] + be[i];
        y[i] = t > 0.f ? t : 0.f;
    }
}

__global__ __launch_bounds__(512) void win_attn_fused(
    const float* __restrict__ qkv,
    const float* __restrict__ wp, const float* __restrict__ bp,
    const float* __restrict__ g1, const float* __restrict__ be1,
    const float* __restrict__ w1, const float* __restrict__ b1,
    const float* __restrict__ g2, const float* __restrict__ be2,
    const float* __restrict__ w2, const float* __restrict__ b2,
    const float* __restrict__ g3, const float* __restrict__ be3,
    const float* __restrict__ w3, const float* __restrict__ b3,
    float* __restrict__ out)
{
    __shared__ __align__(16) unsigned short ks[NTOK * KS2];     // K, all heads
    __shared__ __align__(16) unsigned short vt[CDIM * VTS];     // V^T, rows h*32+d
    __shared__ __align__(16) unsigned short pt[2][NTOK * PTS];  // P per head-half
    __shared__ float psh[NHEADS * NREL];

    const int t = threadIdx.x;
    const int win = blockIdx.x;
    const int b  = win >> 10;
    const int bh = (win >> 5) & 31;
    const int bw = win & 31;

    const int lane = t & 63;
    const int wave = t >> 6;          // 0..7
    const int rg   = wave & 3;        // row-group
    const int hh   = wave >> 2;       // head-half (0: heads 0-2, 1: heads 3-5)
    const int hbase = hh * 3;
    const int lw = lane & 15;
    const int lg = lane >> 4;
    const int rowbase = rg * 16;

    const size_t PL = (size_t)2 * IMG * IMG * CDIM;
    const float* qplane = qkv + (size_t)b * IMG * IMG * CDIM;
    const float* kplane = qplane + PL;
    const float* vplane = kplane + PL;

    auto pixoff = [&](int tok) -> size_t {
        return ((size_t)(bh * 8 + (tok >> 3)) * IMG + (bw * 8 + (tok & 7))) * CDIM;
    };

    // ---------- K: fully contiguous streaming (6 passes x 512 float4) ----------
#pragma unroll
    for (int pass = 0; pass < 6; ++pass) {
        int fidx = t + pass * 512;            // 0..3071
        int s   = fidx / 384;
        int rem = fidx - s * 384;
        int j1  = rem / 48;
        int f   = rem - j1 * 48;
        float4 k4 = *(const float4*)(kplane
                     + ((size_t)(bh * 8 + s) * IMG + (bw * 8 + j1)) * CDIM + f * 4);
        uint2 kk; kk.x = pkbf(k4.x, k4.y); kk.y = pkbf(k4.z, k4.w);
        *(uint2*)&ks[(s * 8 + j1) * KS2 + f * 4] = kk;
    }

    // ---------- V: k'-paired transpose, 3 heads per thread ----------
    {
        const int u  = t & 31;
        const int dg = (t >> 5) & 7;
        const int vh = t >> 8;                // 0..1
        const int ta = (u & 15) + (u >> 4) * 32;
        const int db = dg * 4;
        const int kpa = (u & 15) * 4 + (u >> 4) * 2;
        const size_t offa = pixoff(ta), offb = pixoff(ta + 16);
#pragma unroll
        for (int hi = 0; hi < 3; ++hi) {
            int h = vh * 3 + hi;
            float4 va = *(const float4*)(vplane + offa + h * HD + db);
            float4 vb = *(const float4*)(vplane + offb + h * HD + db);
            int row = h * HD + db;
            *(unsigned*)&vt[(row + 0) * VTS + kpa] = pkbf(va.x, vb.x);
            *(unsigned*)&vt[(row + 1) * VTS + kpa] = pkbf(va.y, vb.y);
            *(unsigned*)&vt[(row + 2) * VTS + kpa] = pkbf(va.z, vb.z);
            *(unsigned*)&vt[(row + 3) * VTS + kpa] = pkbf(va.w, vb.w);
        }
    }

    // ---------- Q: preload this wave's 3 heads ----------
    v8s aq[3];
    {
        const size_t qoff = pixoff(rowbase + lw);
#pragma unroll
        for (int hi = 0; hi < 3; ++hi) {
            const float* qp = qplane + qoff + (hbase + hi) * HD + lg * 8;
            float4 q0 = *(const float4*)qp;
            float4 q1 = *(const float4*)(qp + 4);
            union { v8s v; unsigned x[4]; } au;
            au.x[0] = pkbf(q0.x, q0.y);
            au.x[1] = pkbf(q0.z, q0.w);
            au.x[2] = pkbf(q1.x, q1.y);
            au.x[3] = pkbf(q1.z, q1.w);
            aq[hi] = au.v;
        }
    }

    // ---------- fused DynamicPosBias MLP (threads 0..224) ----------
    if (t < NREL) {
        float x0 = (float)(t / 15 - 7);
        float x1 = (float)(t % 15 - 7);
        float h[PDIM], y[PDIM];
#pragma unroll
        for (int o = 0; o < PDIM; ++o)
            h[o] = x0 * wp[o] + x1 * wp[PDIM + o] + bp[o];
        ln_relu12(h, g1, be1, y);
#pragma unroll
        for (int o = 0; o < PDIM; ++o) {
            float a = b1[o];
#pragma unroll
            for (int i = 0; i < PDIM; ++i) a += y[i] * w1[i * PDIM + o];
            h[o] = a;
        }
        ln_relu12(h, g2, be2, y);
#pragma unroll
        for (int o = 0; o < PDIM; ++o) {
            float a = b2[o];
#pragma unroll
            for (int i = 0; i < PDIM; ++i) a += y[i] * w2[i * PDIM + o];
            h[o] = a;
        }
        ln_relu12(h, g3, be3, y);
#pragma unroll
        for (int o = 0; o < NHEADS; ++o) {
            float a = b3[o];
#pragma unroll
            for (int i = 0; i < PDIM; ++i) a += y[i] * w3[i * NHEADS + o];
            psh[o * NREL + t] = a * INV_SCALE;
        }
    }
    __syncthreads();   // ks, vt, psh visible; only barrier

    // ---------- per-row constants ----------
    int base_r[4];
    size_t ooff[4];
#pragma unroll
    for (int r = 0; r < 4; ++r) {
        int n = rowbase + lg * 4 + r;
        base_r[r] = ((n >> 3) - (lw >> 3) + 7) * 15 + (n & 7) - (lw & 7) + 7;
        ooff[r] = ((size_t)(b * IMG + bh * 8 + (n >> 3)) * IMG
                   + (bw * 8 + (n & 7))) * CDIM;
    }

    // ---------- 3 head iterations per wave ----------
#pragma unroll
    for (int hi = 0; hi < 3; ++hi) {
        const int h = hbase + hi;
        // S' = Q K^T
        v4f acc[4];
#pragma unroll
        for (int ct = 0; ct < 4; ++ct) {
            v4f z = {0.f, 0.f, 0.f, 0.f};
            v8s bfr = *(const v8s*)&ks[(ct * 16 + lw) * KS2 + h * HD + lg * 8];
            acc[ct] = __builtin_amdgcn_mfma_f32_16x16x32_bf16(aq[hi], bfr, z, 0, 0, 0);
        }
        // bias + exp (no max-sub), sum, deferred normalization
        const float* ph = &psh[h * NREL];
        v4f s4 = {0.f, 0.f, 0.f, 0.f};
#pragma unroll
        for (int ct = 0; ct < 4; ++ct)
#pragma unroll
            for (int r = 0; r < 4; ++r) {
                float e = __expf((acc[ct][r] + ph[base_r[r] - ct * 30]) * SCALE);
                acc[ct][r] = e;
                s4[r] += e;
            }
#pragma unroll
        for (int off = 1; off < 16; off <<= 1)
#pragma unroll
            for (int r = 0; r < 4; ++r)
                s4[r] += __shfl_xor(s4[r], off);
        v4f rinv;
#pragma unroll
        for (int r = 0; r < 4; ++r) rinv[r] = __builtin_amdgcn_rcpf(s4[r]);
        // P store (k'-packed b64; wave-private rows within this half's slice)
#pragma unroll
        for (int r = 0; r < 4; ++r) {
            uint2 w;
            w.x = pkbf(acc[0][r], acc[1][r]);
            w.y = pkbf(acc[2][r], acc[3][r]);
            *(uint2*)&pt[hh][(rowbase + lg * 4 + r) * PTS + lw * 4] = w;
        }
        // O = (P V) * rinv
        v8s pa[2];
#pragma unroll
        for (int kt = 0; kt < 2; ++kt)
            pa[kt] = *(const v8s*)&pt[hh][(rowbase + lw) * PTS + kt * 32 + lg * 8];
        v4f acc2[2] = {};
#pragma unroll
        for (int dt = 0; dt < 2; ++dt)
#pragma unroll
            for (int kt = 0; kt < 2; ++kt) {
                v8s vb = *(const v8s*)&vt[(h * HD + dt * 16 + lw) * VTS
                                          + kt * 32 + lg * 8];
                acc2[dt] = __builtin_amdgcn_mfma_f32_16x16x32_bf16(pa[kt], vb, acc2[dt], 0, 0, 0);
            }
#pragma unroll
        for (int dt = 0; dt < 2; ++dt)
#pragma unroll
            for (int r = 0; r < 4; ++r)
                out[ooff[r] + h * HD + dt * 16 + lw] = acc2[dt][r] * rinv[r];
    }
}

extern "C" void kernel_launch(void* const* d_in, const int* in_sizes, int n_in,
                              void* d_out, int out_size, void* d_ws, size_t ws_size,
                              hipStream_t stream) {
    const float* qkv = (const float*)d_in[0];
    win_attn_fused<<<NWIN, 512, 0, stream>>>(
        qkv,
        (const float*)d_in[1], (const float*)d_in[2],
        (const float*)d_in[3], (const float*)d_in[4],
        (const float*)d_in[5], (const float*)d_in[6],
        (const float*)d_in[7], (const float*)d_in[8],
        (const float*)d_in[9], (const float*)d_in[10],
        (const float*)d_in[11], (const float*)d_in[12],
        (const float*)d_in[13], (const float*)d_in[14],
        (float*)d_out);
}